// Round 9
// baseline (259.373 us; speedup 1.0000x reference)
//
#include <hip/hip_runtime.h>

typedef unsigned short u16;
typedef unsigned int u32;
typedef float f32x4 __attribute__((ext_vector_type(4)));
typedef __bf16 bf16x8 __attribute__((ext_vector_type(8)));

#define N_TOK 4096
#define QKV_LD 1536
#define NH 4
#define HID 128
#define C_OUT 512

__device__ __forceinline__ float b2f(u16 u) { return __uint_as_float(((u32)u) << 16); }
__device__ __forceinline__ u16 f2b(float f) {
  u32 u = __float_as_uint(f);
  u32 r = (u + 0x7fffu + ((u >> 16) & 1u)) >> 16;
  return (u16)r;
}

// async global->LDS, 16B per lane. LDS dest = wave-uniform base + lane*16.
typedef const __attribute__((address_space(1))) u32 gu32;
typedef __attribute__((address_space(3))) u32 lu32;
__device__ __forceinline__ void load_lds16(const u16* g, u16* l) {
  __builtin_amdgcn_global_load_lds((gu32*)g, (lu32*)l, 16, 0, 0);
}

// ---------------- all weight transposes in ONE launch ----------------------
// 32x32 tiles; src[b][r][c] f32 -> dst[b][c][r] bf16.
// tile map: [0,768) Wq/Wk/Wv (256 each: b(4) x 16r x 4c), [768,832) Wo,
// [832,1856) W1 (16r x 64c), [1856,2880) W2 (64r x 16c).
__global__ __launch_bounds__(256) void transpose_all(
    const float* __restrict__ Wq, const float* __restrict__ Wk,
    const float* __restrict__ Wv, const float* __restrict__ Wo,
    const float* __restrict__ W1, const float* __restrict__ W2,
    u16* __restrict__ Btqkv, u16* __restrict__ Wot,
    u16* __restrict__ W1t, u16* __restrict__ W2t)
{
  __shared__ u16 tile[32][33];
  const int t = blockIdx.x;
  const float* src; u16* dst; int R, C, r0, c0;
  if (t < 768) {
    int wsel = t >> 8, lt = t & 255;
    int b = lt >> 6, rem = lt & 63;
    R = 512; C = 128;
    const float* W = (wsel == 0) ? Wq : (wsel == 1) ? Wk : Wv;
    src = W + (size_t)b * 65536;
    dst = Btqkv + (size_t)wsel * 262144 + (size_t)b * 65536;
    r0 = (rem >> 2) * 32; c0 = (rem & 3) * 32;
  } else if (t < 832) {
    int lt = t - 768, b = lt >> 4, rem = lt & 15;
    R = 128; C = 128;
    src = Wo + (size_t)b * 16384; dst = Wot + (size_t)b * 16384;
    r0 = (rem >> 2) * 32; c0 = (rem & 3) * 32;
  } else if (t < 1856) {
    int lt = t - 832;
    R = 512; C = 2048; src = W1; dst = W1t;
    r0 = (lt >> 6) * 32; c0 = (lt & 63) * 32;
  } else {
    int lt = t - 1856;
    R = 2048; C = 512; src = W2; dst = W2t;
    r0 = (lt >> 4) * 32; c0 = (lt & 15) * 32;
  }
  const int tx = threadIdx.x & 31, ty = threadIdx.x >> 5;  // 32 x 8
#pragma unroll
  for (int i = 0; i < 32; i += 8)
    tile[ty + i][tx] = f2b(src[(size_t)(r0 + ty + i) * C + c0 + tx]);
  __syncthreads();
#pragma unroll
  for (int i = 0; i < 32; i += 8)
    dst[(size_t)(c0 + ty + i) * R + r0 + tx] = tile[tx][ty + i];
}

// ---------------- layernorm (optionally + relu), block per row -------------
__global__ __launch_bounds__(256) void ln_kernel(
    const void* __restrict__ x, const float* __restrict__ g,
    const float* __restrict__ b, u16* __restrict__ y,
    int C, int in_f32, int do_relu)
{
  int row = blockIdx.x;
  int tid = threadIdx.x;
  const float* xf = (const float*)x + (size_t)row * C;
  const u16* xh = (const u16*)x + (size_t)row * C;
  float s1 = 0.f, s2 = 0.f;
  for (int c = tid; c < C; c += 256) {
    float v = in_f32 ? xf[c] : b2f(xh[c]);
    s1 += v; s2 += v * v;
  }
  __shared__ float red[2][4];
  for (int o = 32; o; o >>= 1) { s1 += __shfl_down(s1, o); s2 += __shfl_down(s2, o); }
  int lane = tid & 63, w = tid >> 6;
  if (lane == 0) { red[0][w] = s1; red[1][w] = s2; }
  __syncthreads();
  s1 = red[0][0] + red[0][1] + red[0][2] + red[0][3];
  s2 = red[1][0] + red[1][1] + red[1][2] + red[1][3];
  float mean = s1 / C;
  float var = s2 / C - mean * mean;
  float rs = rsqrtf(fmaxf(var, 0.f) + 1e-5f);
  u16* yr = y + (size_t)row * C;
  for (int c = tid; c < C; c += 256) {
    float v = in_f32 ? xf[c] : b2f(xh[c]);
    v = (v - mean) * rs * g[c] + b[c];
    if (do_relu) v = fmaxf(v, 0.f);
    yr[c] = f2b(v);
  }
}

// ---------------- 128x128-tile MFMA GEMM, m97 structure --------------------
// 256 threads / 4 waves; each wave computes 64x64 (4x4 of 16x16x32 MFMA).
// global_load_lds width-16 staging into UNPADDED BK=32 LDS tiles
// (wave-uniform base + lane*16B contract; chunk c = seg*64+lane maps to
// row c>>2, cols (c&3)*8 — byte-contiguous). 2-way LDS bank aliasing on
// fragment ds_read_b128 is free (m136).
#define BK 32
__global__ __launch_bounds__(256) void gemm128(
    const u16* __restrict__ A, int lda,
    const u16* __restrict__ Bt,
    void* __restrict__ C, int ldc, int outf32,
    const float* __restrict__ res,
    int Kslice, int Ktot, int bd, int atomic)
{
  __shared__ alignas(16) u16 As[128 * BK];
  __shared__ alignas(16) u16 Bs[128 * BK];
  const int bn = blockIdx.x, bm = blockIdx.y;
  const int m0 = bm * 128, n0 = bn * 128;
  const int kbase = blockIdx.z * Kslice;
  const int abase = (bd ? bn * Ktot : 0) + kbase;
  const int tid = threadIdx.x;
  const int lane = tid & 63, w = tid >> 6;
  const int wm = (w & 1) * 64, wn = (w >> 1) * 64;
  const int l16 = lane & 15, quad = lane >> 4;

  // staging: 8 segments (2 per wave) x 64 lanes x 16 B = 8 KB per matrix
  const int c0 = w * 128 + lane;       // chunk for segment 2w
  const int c1 = c0 + 64;              // chunk for segment 2w+1
  const u16* pa0 = A + (size_t)(m0 + (c0 >> 2)) * lda + abase + (c0 & 3) * 8;
  const u16* pa1 = A + (size_t)(m0 + (c1 >> 2)) * lda + abase + (c1 & 3) * 8;
  const u16* pb0 = Bt + (size_t)(n0 + (c0 >> 2)) * Ktot + kbase + (c0 & 3) * 8;
  const u16* pb1 = Bt + (size_t)(n0 + (c1 >> 2)) * Ktot + kbase + (c1 & 3) * 8;
  u16* la0 = &As[(w * 2 + 0) * 512];   // wave-uniform LDS segment bases
  u16* la1 = &As[(w * 2 + 1) * 512];
  u16* lb0 = &Bs[(w * 2 + 0) * 512];
  u16* lb1 = &Bs[(w * 2 + 1) * 512];

  f32x4 acc[4][4];
#pragma unroll
  for (int i = 0; i < 4; i++)
#pragma unroll
    for (int j = 0; j < 4; j++) acc[i][j] = (f32x4){0.f, 0.f, 0.f, 0.f};

  for (int kk = 0; kk < Kslice; kk += BK) {
    load_lds16(pa0, la0); load_lds16(pa1, la1);
    load_lds16(pb0, lb0); load_lds16(pb1, lb1);
    pa0 += BK; pa1 += BK; pb0 += BK; pb1 += BK;
    __syncthreads();                   // drains vmcnt -> LDS valid
    bf16x8 af[4], bf[4];
#pragma unroll
    for (int mt = 0; mt < 4; mt++)
      af[mt] = *(const bf16x8*)&As[(wm + mt * 16 + l16) * BK + quad * 8];
#pragma unroll
    for (int nt = 0; nt < 4; nt++)
      bf[nt] = *(const bf16x8*)&Bs[(wn + nt * 16 + l16) * BK + quad * 8];
#pragma unroll
    for (int mt = 0; mt < 4; mt++)
#pragma unroll
      for (int nt = 0; nt < 4; nt++)
        acc[mt][nt] = __builtin_amdgcn_mfma_f32_16x16x32_bf16(
            af[mt], bf[nt], acc[mt][nt], 0, 0, 0);
    __syncthreads();                   // protect LDS before next overwrite
  }

#pragma unroll
  for (int mt = 0; mt < 4; mt++)
#pragma unroll
    for (int nt = 0; nt < 4; nt++)
#pragma unroll
      for (int r = 0; r < 4; r++) {
        int gr = m0 + wm + mt * 16 + quad * 4 + r;
        int gc = n0 + wn + nt * 16 + l16;
        size_t off = (size_t)gr * ldc + gc;
        float v = acc[mt][nt][r];
        if (atomic) {
          atomicAdd((float*)C + off, v);
        } else {
          if (res) v += res[off];
          if (outf32) ((float*)C)[off] = v;
          else        ((u16*)C)[off] = f2b(v);
        }
      }
}

// ---------------- banded attention, MFMA QK^T + PV (round-8, unchanged) ----
#define TQ 16
#define BAND 112
#define KROW 136
#define PROW 120
__global__ __launch_bounds__(256) void attn_mfma(
    const u16* __restrict__ qkv, const float* __restrict__ pos,
    const float* __restrict__ ori, const int* __restrict__ batch,
    u16* __restrict__ ot)
{
  const int h = blockIdx.y;
  const int i0 = blockIdx.x * TQ;
  const int j0 = i0 - 48;
  const int tid = threadIdx.x;
  const int lane = tid & 63, w = tid >> 6;
  const int l16 = lane & 15, quad = lane >> 4;

  __shared__ u16 kv[128 * KROW];
  __shared__ u16 qp[TQ * KROW];
  __shared__ float ps[TQ * PROW];
  __shared__ float bpx[BAND], bpy[BAND], bpz[BAND];
  __shared__ float box_[BAND], boy_[BAND], boz_[BAND];
  __shared__ int bb[BAND];

  for (int t = tid; t < BAND; t += 256) {
    int j = j0 + t;
    if (j >= 0 && j < N_TOK) {
      bpx[t] = pos[j * 3 + 0]; bpy[t] = pos[j * 3 + 1]; bpz[t] = pos[j * 3 + 2];
      box_[t] = ori[j * 3 + 0]; boy_[t] = ori[j * 3 + 1]; boz_[t] = ori[j * 3 + 2];
      bb[t] = batch[j];
    } else {
      bpx[t] = bpy[t] = bpz[t] = 0.f;
      box_[t] = boy_[t] = boz_[t] = 0.f;
      bb[t] = -12345;
    }
  }
  for (int idx = tid; idx < BAND * 16; idx += 256) {
    int t = idx >> 4, c8 = (idx & 15) * 8;
    int j = j0 + t;
    int4 val = {0, 0, 0, 0};
    if (j >= 0 && j < N_TOK)
      val = *(const int4*)&qkv[(size_t)j * QKV_LD + 512 + h * HID + c8];
    *(int4*)&kv[t * KROW + c8] = val;
  }
  {
    int q = tid >> 4, c8 = (tid & 15) * 8;
    *(int4*)&qp[q * KROW + c8] =
        *(const int4*)&qkv[(size_t)(i0 + q) * QKV_LD + h * HID + c8];
  }
  __syncthreads();

  {
    bf16x8 af[4];
#pragma unroll
    for (int kc = 0; kc < 4; kc++)
      af[kc] = *(const bf16x8*)&qp[l16 * KROW + kc * 32 + quad * 8];
#pragma unroll
    for (int ti = 0; ti < 2; ti++) {
      int tt = w + ti * 4;
      if (tt < 7) {
        f32x4 acc = (f32x4){0.f, 0.f, 0.f, 0.f};
#pragma unroll
        for (int kc = 0; kc < 4; kc++) {
          bf16x8 bf = *(const bf16x8*)&kv[(tt * 16 + l16) * KROW + kc * 32 + quad * 8];
          acc = __builtin_amdgcn_mfma_f32_16x16x32_bf16(af[kc], bf, acc, 0, 0, 0);
        }
        int t = tt * 16 + l16;
#pragma unroll
        for (int r = 0; r < 4; r++) {
          int q = quad * 4 + r, iq = q + 48;
          int dseq = iq - t;
          bool ok = (bb[t] == bb[iq]) && (dseq <= 48) && (dseq >= -48);
          {
#pragma clang fp contract(off)
            float dx = bpx[iq] - bpx[t], dy = bpy[iq] - bpy[t], dz = bpz[iq] - bpz[t];
            float d2 = dx * dx + dy * dy + dz * dz;
            ok = ok && (d2 <= 1.0f);
          }
          float s = -1e9f;
          if (ok) {
            float gb = box_[iq] * box_[t] + boy_[iq] * boy_[t] + boz_[iq] * boz_[t];
            s = acc[r] * 0.08838834764831845f + gb;
          }
          ps[q * PROW + t] = s;
        }
      }
    }
  }
  __syncthreads();

  for (int idx = tid; idx < BAND * 32; idx += 256) {
    int t = idx >> 5, d4 = (idx & 31) * 4;
    int j = j0 + t;
    uint2 val; val.x = 0; val.y = 0;
    if (j >= 0 && j < N_TOK)
      val = *(const uint2*)&qkv[(size_t)j * QKV_LD + 1024 + h * HID + d4];
    u16 e[4] = {(u16)val.x, (u16)(val.x >> 16), (u16)val.y, (u16)(val.y >> 16)};
#pragma unroll
    for (int jj = 0; jj < 4; jj++) {
      int dd = (jj + tid) & 3;
      kv[(d4 + dd) * KROW + t] = e[dd];
    }
  }
  for (int idx = tid; idx < 128 * 16; idx += 256) {
    int d = idx >> 4, t = BAND + (idx & 15);
    kv[d * KROW + t] = 0;
  }
  if (tid < TQ) {
    float m = -1e30f;
    for (int t = 0; t < BAND; t++) m = fmaxf(m, ps[tid * PROW + t]);
    float s = 0.f;
    for (int t = 0; t < BAND; t++) {
      float e = __expf(ps[tid * PROW + t] - m);
      ps[tid * PROW + t] = e; s += e;
    }
    float inv = 1.f / s;
    for (int t = 0; t < BAND; t++) ps[tid * PROW + t] *= inv;
  }
  __syncthreads();

  {
    int q = tid >> 4, t0 = (tid & 15) * 8;
    u16 tmp[8];
#pragma unroll
    for (int i = 0; i < 8; i++) {
      int t = t0 + i;
      tmp[i] = (t < BAND) ? f2b(ps[q * PROW + t]) : (u16)0;
    }
    *(int4*)&qp[q * KROW + t0] = *(const int4*)tmp;
  }
  __syncthreads();

  {
    bf16x8 paf[4];
#pragma unroll
    for (int kc = 0; kc < 4; kc++)
      paf[kc] = *(const bf16x8*)&qp[l16 * KROW + kc * 32 + quad * 8];
#pragma unroll
    for (int ti = 0; ti < 2; ti++) {
      int dt = w + ti * 4;
      f32x4 acc = (f32x4){0.f, 0.f, 0.f, 0.f};
#pragma unroll
      for (int kc = 0; kc < 4; kc++) {
        bf16x8 bf = *(const bf16x8*)&kv[(dt * 16 + l16) * KROW + kc * 32 + quad * 8];
        acc = __builtin_amdgcn_mfma_f32_16x16x32_bf16(paf[kc], bf, acc, 0, 0, 0);
      }
#pragma unroll
      for (int r = 0; r < 4; r++) {
        int q = quad * 4 + r;
        ot[(size_t)(i0 + q) * C_OUT + h * HID + dt * 16 + l16] = f2b(acc[r]);
      }
    }
  }
}

// ---------------- launcher --------------------------------------------------
// Inputs f32, ints i32, OUTPUT f32. d_ws is 256 MB (round-8 fill evidence) —
// no aliasing needed. Layout:
//   [0,4M) xn  [4,16M) qkv  [16,20M) ot  [20,24M) x1n  [24,40M) h
//   [40,41.5M) Btqkv  [42,42.25M) Wot  [43,45M) W1t  [45,47M) W2t
#define MB (1048576)
extern "C" void kernel_launch(void* const* d_in, const int* in_sizes, int n_in,
                              void* d_out, int out_size, void* d_ws, size_t ws_size,
                              hipStream_t stream) {
  const float* x    = (const float*)d_in[0];
  const float* pos  = (const float*)d_in[1];
  const float* ori  = (const float*)d_in[2];
  const int*   batch = (const int*)d_in[4];
  const float* ln1g = (const float*)d_in[5];
  const float* ln1b = (const float*)d_in[6];
  const float* ln2g = (const float*)d_in[7];
  const float* ln2b = (const float*)d_in[8];
  const float* Wq = (const float*)d_in[9];
  const float* Wk = (const float*)d_in[10];
  const float* Wv = (const float*)d_in[11];
  const float* Wo = (const float*)d_in[12];
  const float* lnmg = (const float*)d_in[13];
  const float* lnmb = (const float*)d_in[14];
  const float* W1 = (const float*)d_in[15];
  const float* W2 = (const float*)d_in[16];
  float* out = (float*)d_out;

  char* ws = (char*)d_ws;
  u16* xn    = (u16*)(ws + 0);
  u16* qkv   = (u16*)(ws + 4 * MB);
  u16* ot    = (u16*)(ws + 16 * MB);
  u16* x1n   = (u16*)(ws + 20 * MB);
  u16* h     = (u16*)(ws + 24 * MB);
  u16* Btqkv = (u16*)(ws + 40 * MB);
  u16* Wot   = (u16*)(ws + 42 * MB);
  u16* W1t   = (u16*)(ws + 43 * MB);
  u16* W2t   = (u16*)(ws + 45 * MB);

  // all weight transposes, one launch
  transpose_all<<<dim3(2880), 256, 0, stream>>>(Wq, Wk, Wv, Wo, W1, W2,
                                                Btqkv, Wot, W1t, W2t);
  // ln1
  ln_kernel<<<dim3(4096), 256, 0, stream>>>(x, ln1g, ln1b, xn, 512, 1, 0);
  // qkv = xn @ [Wq|Wk|Wv]
  gemm128<<<dim3(12, 32, 1), 256, 0, stream>>>(xn, 512, Btqkv, qkv, QKV_LD, 0,
                                               nullptr, 512, 512, 0, 0);
  // attention (MFMA)
  attn_mfma<<<dim3(256, NH), 256, 0, stream>>>(qkv, pos, ori, batch, ot);
  // x1 = blockdiag(ot @ Wo) + x -> out (f32)
  gemm128<<<dim3(4, 32, 1), 256, 0, stream>>>(ot, 512, Wot, out, 512, 1,
                                              x, 128, 128, 1, 0);
  // ln2
  ln_kernel<<<dim3(4096), 256, 0, stream>>>(out, ln2g, ln2b, x1n, 512, 1, 0);
  // h = x1n @ W1
  gemm128<<<dim3(16, 32, 1), 256, 0, stream>>>(x1n, 512, W1t, h, 2048, 0,
                                               nullptr, 512, 512, 0, 0);
  // h = relu(LN(h))
  ln_kernel<<<dim3(4096), 256, 0, stream>>>(h, lnmg, lnmb, h, 2048, 0, 1);
  // out += h @ W2  (split-K x4, atomic f32; out already holds x1)
  gemm128<<<dim3(4, 32, 4), 256, 0, stream>>>(h, 2048, W2t, out, 512, 1,
                                              nullptr, 512, 2048, 0, 1);
}

// Round 10
// 250.792 us; speedup vs baseline: 1.0342x; 1.0342x over previous
//
#include <hip/hip_runtime.h>

typedef unsigned short u16;
typedef unsigned int u32;
typedef float f32x4 __attribute__((ext_vector_type(4)));
typedef __bf16 bf16x8 __attribute__((ext_vector_type(8)));

#define N_TOK 4096
#define QKV_LD 1536
#define NH 4
#define HID 128
#define C_OUT 512

__device__ __forceinline__ float b2f(u16 u) { return __uint_as_float(((u32)u) << 16); }
__device__ __forceinline__ u16 f2b(float f) {
  u32 u = __float_as_uint(f);
  u32 r = (u + 0x7fffu + ((u >> 16) & 1u)) >> 16;
  return (u16)r;
}

// ---------------- prep: all weight transposes + ln1, ONE launch ------------
// blocks [0,2880): 32x32 transpose tiles (f32 -> bf16, [b][r][c]->[b][c][r]):
//   [0,768) Wq/Wk/Wv, [768,832) Wo, [832,1856) W1, [1856,2880) W2.
// blocks [2880,6976): ln1 row (t-2880) of x -> xn.
__global__ __launch_bounds__(256) void prep_kernel(
    const float* __restrict__ Wq, const float* __restrict__ Wk,
    const float* __restrict__ Wv, const float* __restrict__ Wo,
    const float* __restrict__ W1, const float* __restrict__ W2,
    u16* __restrict__ Btqkv, u16* __restrict__ Wot,
    u16* __restrict__ W1t, u16* __restrict__ W2t,
    const float* __restrict__ x, const float* __restrict__ ln1g,
    const float* __restrict__ ln1b, u16* __restrict__ xn)
{
  const int t = blockIdx.x;
  const int tid = threadIdx.x;
  if (t < 2880) {
    __shared__ u16 tile[32][33];
    const float* src; u16* dst; int R, C, r0, c0;
    if (t < 768) {
      int wsel = t >> 8, lt = t & 255;
      int b = lt >> 6, rem = lt & 63;
      R = 512; C = 128;
      const float* W = (wsel == 0) ? Wq : (wsel == 1) ? Wk : Wv;
      src = W + (size_t)b * 65536;
      dst = Btqkv + (size_t)wsel * 262144 + (size_t)b * 65536;
      r0 = (rem >> 2) * 32; c0 = (rem & 3) * 32;
    } else if (t < 832) {
      int lt = t - 768, b = lt >> 4, rem = lt & 15;
      R = 128; C = 128;
      src = Wo + (size_t)b * 16384; dst = Wot + (size_t)b * 16384;
      r0 = (rem >> 2) * 32; c0 = (rem & 3) * 32;
    } else if (t < 1856) {
      int lt = t - 832;
      R = 512; C = 2048; src = W1; dst = W1t;
      r0 = (lt >> 6) * 32; c0 = (lt & 63) * 32;
    } else {
      int lt = t - 1856;
      R = 2048; C = 512; src = W2; dst = W2t;
      r0 = (lt >> 4) * 32; c0 = (lt & 15) * 32;
    }
    const int tx = tid & 31, ty = tid >> 5;
#pragma unroll
    for (int i = 0; i < 32; i += 8)
      tile[ty + i][tx] = f2b(src[(size_t)(r0 + ty + i) * C + c0 + tx]);
    __syncthreads();
#pragma unroll
    for (int i = 0; i < 32; i += 8)
      dst[(size_t)(c0 + ty + i) * R + r0 + tx] = tile[tx][ty + i];
  } else {
    // ln1 on row (t-2880)
    int row = t - 2880;
    const float* xf = x + (size_t)row * 512;
    float s1 = 0.f, s2 = 0.f;
    for (int c = tid; c < 512; c += 256) { float v = xf[c]; s1 += v; s2 += v * v; }
    __shared__ float red[2][4];
    for (int o = 32; o; o >>= 1) { s1 += __shfl_down(s1, o); s2 += __shfl_down(s2, o); }
    int lane = tid & 63, w = tid >> 6;
    if (lane == 0) { red[0][w] = s1; red[1][w] = s2; }
    __syncthreads();
    s1 = red[0][0] + red[0][1] + red[0][2] + red[0][3];
    s2 = red[1][0] + red[1][1] + red[1][2] + red[1][3];
    float mean = s1 / 512, var = s2 / 512 - mean * mean;
    float rs = rsqrtf(fmaxf(var, 0.f) + 1e-5f);
    u16* yr = xn + (size_t)row * 512;
    for (int c = tid; c < 512; c += 256)
      yr[c] = f2b((xf[c] - mean) * rs * ln1g[c] + ln1b[c]);
  }
}

// ---------------- layernorm (+relu) for lnm --------------------------------
__global__ __launch_bounds__(256) void ln_kernel(
    const void* __restrict__ x, const float* __restrict__ g,
    const float* __restrict__ b, u16* __restrict__ y,
    int C, int in_f32, int do_relu)
{
  int row = blockIdx.x;
  int tid = threadIdx.x;
  const float* xf = (const float*)x + (size_t)row * C;
  const u16* xh = (const u16*)x + (size_t)row * C;
  float s1 = 0.f, s2 = 0.f;
  for (int c = tid; c < C; c += 256) {
    float v = in_f32 ? xf[c] : b2f(xh[c]);
    s1 += v; s2 += v * v;
  }
  __shared__ float red[2][4];
  for (int o = 32; o; o >>= 1) { s1 += __shfl_down(s1, o); s2 += __shfl_down(s2, o); }
  int lane = tid & 63, w = tid >> 6;
  if (lane == 0) { red[0][w] = s1; red[1][w] = s2; }
  __syncthreads();
  s1 = red[0][0] + red[0][1] + red[0][2] + red[0][3];
  s2 = red[1][0] + red[1][1] + red[1][2] + red[1][3];
  float mean = s1 / C;
  float var = s2 / C - mean * mean;
  float rs = rsqrtf(fmaxf(var, 0.f) + 1e-5f);
  u16* yr = y + (size_t)row * C;
  for (int c = tid; c < C; c += 256) {
    float v = in_f32 ? xf[c] : b2f(xh[c]);
    v = (v - mean) * rs * g[c] + b[c];
    if (do_relu) v = fmaxf(v, 0.f);
    yr[c] = f2b(v);
  }
}

// ---------------- 128x128-tile MFMA GEMM (round-8 proven structure) --------
#define LDK 40
__global__ __launch_bounds__(512, 4) void gemm128(
    const u16* __restrict__ A, int lda,
    const u16* __restrict__ Bt,
    void* __restrict__ C, int ldc, int outf32,
    const float* __restrict__ res,
    int Kslice, int Ktot, int bd, int atomic)
{
  __shared__ u16 As[128 * LDK];
  __shared__ u16 Bs[128 * LDK];
  const int bn = blockIdx.x, bm = blockIdx.y;
  const int m0 = bm * 128, n0 = bn * 128;
  const int kbase = blockIdx.z * Kslice;
  const int abase = (bd ? bn * Ktot : 0) + kbase;
  const int tid = threadIdx.x;
  const int lane = tid & 63, w = tid >> 6;
  const int wm = (w & 1) * 64;
  const int wn = (w >> 1) * 32;
  const int l16 = lane & 15, quad = lane >> 4;

  const int sr = tid >> 2, sc = (tid & 3) * 8;
  const u16* PA = A + (size_t)(m0 + sr) * lda + abase + sc;
  const u16* PB = Bt + (size_t)(n0 + sr) * Ktot + kbase + sc;

  f32x4 acc[4][2];
#pragma unroll
  for (int i = 0; i < 4; i++)
#pragma unroll
    for (int j = 0; j < 2; j++) acc[i][j] = (f32x4){0.f, 0.f, 0.f, 0.f};

  int4 pa = *(const int4*)PA;
  int4 pb = *(const int4*)PB;
  for (int kk = 0; kk < Kslice; kk += 32) {
    *(int4*)&As[sr * LDK + sc] = pa;
    *(int4*)&Bs[sr * LDK + sc] = pb;
    __syncthreads();
    if (kk + 32 < Kslice) {
      PA += 32; pa = *(const int4*)PA;
      PB += 32; pb = *(const int4*)PB;
    }
    bf16x8 af[4], bfr[2];
#pragma unroll
    for (int mt = 0; mt < 4; mt++)
      af[mt] = *(const bf16x8*)&As[(wm + mt * 16 + l16) * LDK + quad * 8];
#pragma unroll
    for (int nt = 0; nt < 2; nt++)
      bfr[nt] = *(const bf16x8*)&Bs[(wn + nt * 16 + l16) * LDK + quad * 8];
#pragma unroll
    for (int mt = 0; mt < 4; mt++)
#pragma unroll
      for (int nt = 0; nt < 2; nt++)
        acc[mt][nt] = __builtin_amdgcn_mfma_f32_16x16x32_bf16(
            af[mt], bfr[nt], acc[mt][nt], 0, 0, 0);
    __syncthreads();
  }

#pragma unroll
  for (int mt = 0; mt < 4; mt++)
#pragma unroll
    for (int nt = 0; nt < 2; nt++)
#pragma unroll
      for (int r = 0; r < 4; r++) {
        int gr = m0 + wm + mt * 16 + quad * 4 + r;
        int gc = n0 + wn + nt * 16 + l16;
        size_t off = (size_t)gr * ldc + gc;
        float v = acc[mt][nt][r];
        if (atomic) {
          atomicAdd((float*)C + off, v);
        } else {
          if (res) v += res[off];
          if (outf32) ((float*)C)[off] = v;
          else        ((u16*)C)[off] = f2b(v);
        }
      }
}

// ---------------- fused attention + Wo + residual + ln2 --------------------
// One block per 16-row tile (grid 256); loops all 4 heads internally.
// Writes out = x1 (f32) and x1n = LN2(x1) (bf16). Eliminates Wo gemm + ln2.
#define TQ 16
#define BAND 112
#define KROW 136
#define PROW 128
__global__ __launch_bounds__(256) void attn_fused(
    const u16* __restrict__ qkv, const float* __restrict__ pos,
    const float* __restrict__ ori, const int* __restrict__ batch,
    const u16* __restrict__ Wot, const float* __restrict__ x,
    const float* __restrict__ ln2g, const float* __restrict__ ln2b,
    float* __restrict__ out, u16* __restrict__ x1n)
{
  const int i0 = blockIdx.x * TQ;
  const int j0 = i0 - 48;
  const int tid = threadIdx.x;
  const int lane = tid & 63, w = tid >> 6;
  const int l16 = lane & 15, quad = lane >> 4;

  __shared__ u16 kv[128 * KROW];   // K band, then V^T (per head)
  __shared__ u16 qp[TQ * KROW];    // Q, then P bf16 (per head)
  __shared__ u16 ob[TQ * KROW];    // O_h bf16 (per head)
  __shared__ float ps[TQ * PROW];  // scores/probs
  __shared__ float bpx[BAND], bpy[BAND], bpz[BAND];
  __shared__ float box_[BAND], boy_[BAND], boz_[BAND];
  __shared__ int bb[BAND];
  __shared__ float stq[TQ][2];

  // geometry (once)
  for (int t = tid; t < BAND; t += 256) {
    int j = j0 + t;
    if (j >= 0 && j < N_TOK) {
      bpx[t] = pos[j * 3 + 0]; bpy[t] = pos[j * 3 + 1]; bpz[t] = pos[j * 3 + 2];
      box_[t] = ori[j * 3 + 0]; boy_[t] = ori[j * 3 + 1]; boz_[t] = ori[j * 3 + 2];
      bb[t] = batch[j];
    } else {
      bpx[t] = bpy[t] = bpz[t] = 0.f;
      box_[t] = boy_[t] = boz_[t] = 0.f;
      bb[t] = -12345;
    }
  }

  float accw[NH][2][4];  // x1 contribution: [h][et][r], col = h*128+(w+et*4)*16+l16

  for (int h = 0; h < NH; h++) {
    __syncthreads();  // geom ready (h=0) / prev head's ob reads done
    // ---- stage K_h, Q_h ----
    for (int idx = tid; idx < BAND * 16; idx += 256) {
      int t = idx >> 4, c8 = (idx & 15) * 8;
      int j = j0 + t;
      int4 val = {0, 0, 0, 0};
      if (j >= 0 && j < N_TOK)
        val = *(const int4*)&qkv[(size_t)j * QKV_LD + 512 + h * HID + c8];
      *(int4*)&kv[t * KROW + c8] = val;
    }
    {
      int q = tid >> 4, c8 = (tid & 15) * 8;
      *(int4*)&qp[q * KROW + c8] =
          *(const int4*)&qkv[(size_t)(i0 + q) * QKV_LD + h * HID + c8];
    }
    __syncthreads();
    // ---- scores ----
    {
      bf16x8 af[4];
#pragma unroll
      for (int kc = 0; kc < 4; kc++)
        af[kc] = *(const bf16x8*)&qp[l16 * KROW + kc * 32 + quad * 8];
#pragma unroll
      for (int ti = 0; ti < 2; ti++) {
        int tt = w + ti * 4;
        if (tt < 7) {
          f32x4 acc = (f32x4){0.f, 0.f, 0.f, 0.f};
#pragma unroll
          for (int kc = 0; kc < 4; kc++) {
            bf16x8 bf = *(const bf16x8*)&kv[(tt * 16 + l16) * KROW + kc * 32 + quad * 8];
            acc = __builtin_amdgcn_mfma_f32_16x16x32_bf16(af[kc], bf, acc, 0, 0, 0);
          }
          int t = tt * 16 + l16;
#pragma unroll
          for (int r = 0; r < 4; r++) {
            int q = quad * 4 + r, iq = q + 48;
            int dseq = iq - t;
            bool ok = (bb[t] == bb[iq]) && (dseq <= 48) && (dseq >= -48);
            {
#pragma clang fp contract(off)
              float dx = bpx[iq] - bpx[t], dy = bpy[iq] - bpy[t], dz = bpz[iq] - bpz[t];
              float d2 = dx * dx + dy * dy + dz * dz;
              ok = ok && (d2 <= 1.0f);
            }
            float s = -1e9f;
            if (ok) {
              float gb = box_[iq] * box_[t] + boy_[iq] * boy_[t] + boz_[iq] * boz_[t];
              s = acc[r] * 0.08838834764831845f + gb;
            }
            ps[q * PROW + t] = s;
          }
        }
      }
    }
    __syncthreads();
    // ---- stage V^T + softmax ----
    for (int idx = tid; idx < BAND * 32; idx += 256) {
      int t = idx >> 5, d4 = (idx & 31) * 4;
      int j = j0 + t;
      uint2 val; val.x = 0; val.y = 0;
      if (j >= 0 && j < N_TOK)
        val = *(const uint2*)&qkv[(size_t)j * QKV_LD + 1024 + h * HID + d4];
      u16 e[4] = {(u16)val.x, (u16)(val.x >> 16), (u16)val.y, (u16)(val.y >> 16)};
#pragma unroll
      for (int jj = 0; jj < 4; jj++) {
        int dd = (jj + tid) & 3;
        kv[(d4 + dd) * KROW + t] = e[dd];
      }
    }
    for (int idx = tid; idx < 128 * 16; idx += 256) {
      int d = idx >> 4, t = BAND + (idx & 15);
      kv[d * KROW + t] = 0;
    }
    if (tid < TQ) {
      float m = -1e30f;
      for (int t = 0; t < BAND; t++) m = fmaxf(m, ps[tid * PROW + t]);
      float s = 0.f;
      for (int t = 0; t < BAND; t++) {
        float e = __expf(ps[tid * PROW + t] - m);
        ps[tid * PROW + t] = e; s += e;
      }
      float inv = 1.f / s;
      for (int t = 0; t < BAND; t++) ps[tid * PROW + t] *= inv;
    }
    __syncthreads();
    // ---- P -> bf16 ----
    {
      int q = tid >> 4, t0 = (tid & 15) * 8;
      u16 tmp[8];
#pragma unroll
      for (int i = 0; i < 8; i++) {
        int t = t0 + i;
        tmp[i] = (t < BAND) ? f2b(ps[q * PROW + t]) : (u16)0;
      }
      *(int4*)&qp[q * KROW + t0] = *(const int4*)tmp;
    }
    __syncthreads();
    // ---- PV -> O_h (bf16 in ob) ----
    {
      bf16x8 paf[4];
#pragma unroll
      for (int kc = 0; kc < 4; kc++)
        paf[kc] = *(const bf16x8*)&qp[l16 * KROW + kc * 32 + quad * 8];
#pragma unroll
      for (int ti = 0; ti < 2; ti++) {
        int dt = w + ti * 4;
        f32x4 acc = (f32x4){0.f, 0.f, 0.f, 0.f};
#pragma unroll
        for (int kc = 0; kc < 4; kc++) {
          bf16x8 bf = *(const bf16x8*)&kv[(dt * 16 + l16) * KROW + kc * 32 + quad * 8];
          acc = __builtin_amdgcn_mfma_f32_16x16x32_bf16(paf[kc], bf, acc, 0, 0, 0);
        }
#pragma unroll
        for (int r = 0; r < 4; r++)
          ob[(quad * 4 + r) * KROW + dt * 16 + l16] = f2b(acc[r]);
      }
    }
    __syncthreads();
    // ---- Wo: x1_h = O_h @ Wo_h (B-frags straight from global Wot) ----
    {
      bf16x8 oaf[4];
#pragma unroll
      for (int kc = 0; kc < 4; kc++)
        oaf[kc] = *(const bf16x8*)&ob[l16 * KROW + kc * 32 + quad * 8];
#pragma unroll
      for (int et = 0; et < 2; et++) {
        int etile = w + et * 4;
        f32x4 acc = (f32x4){0.f, 0.f, 0.f, 0.f};
#pragma unroll
        for (int kc = 0; kc < 4; kc++) {
          bf16x8 wb = *(const bf16x8*)&Wot[h * 16384 + (etile * 16 + l16) * 128 + kc * 32 + quad * 8];
          acc = __builtin_amdgcn_mfma_f32_16x16x32_bf16(oaf[kc], wb, acc, 0, 0, 0);
        }
#pragma unroll
        for (int r = 0; r < 4; r++) accw[h][et][r] = acc[r];
      }
    }
  }
  __syncthreads();

  // ---- residual + ln2 partials (kv dead -> reuse as f32 scratch) ----
  float* p1 = (float*)kv;          // [16][64]
  float* p2 = p1 + 1024;
#pragma unroll
  for (int r = 0; r < 4; r++) {
    int q = quad * 4 + r;
    float s1 = 0.f, s2 = 0.f;
#pragma unroll
    for (int h = 0; h < NH; h++)
#pragma unroll
      for (int et = 0; et < 2; et++) {
        int c = h * 128 + (w + et * 4) * 16 + l16;
        float v = accw[h][et][r] + x[(size_t)(i0 + q) * C_OUT + c];
        accw[h][et][r] = v;
        s1 += v; s2 += v * v;
      }
    p1[q * 64 + w * 16 + l16] = s1;
    p2[q * 64 + w * 16 + l16] = s2;
  }
  __syncthreads();
  if (tid < TQ) {
    float s1 = 0.f, s2 = 0.f;
    for (int k = 0; k < 64; k++) { s1 += p1[tid * 64 + k]; s2 += p2[tid * 64 + k]; }
    float mean = s1 / C_OUT;
    float var = s2 / C_OUT - mean * mean;
    stq[tid][0] = mean;
    stq[tid][1] = rsqrtf(fmaxf(var, 0.f) + 1e-5f);
  }
  __syncthreads();
  // ---- write out (x1 f32) + x1n (bf16) ----
#pragma unroll
  for (int r = 0; r < 4; r++) {
    int q = quad * 4 + r;
    float mean = stq[q][0], rs = stq[q][1];
#pragma unroll
    for (int h = 0; h < NH; h++)
#pragma unroll
      for (int et = 0; et < 2; et++) {
        int c = h * 128 + (w + et * 4) * 16 + l16;
        size_t off = (size_t)(i0 + q) * C_OUT + c;
        float v = accw[h][et][r];
        out[off] = v;
        x1n[off] = f2b((v - mean) * rs * ln2g[c] + ln2b[c]);
      }
  }
}

// ---------------- launcher --------------------------------------------------
// Inputs f32, ints i32, OUTPUT f32. 6 launches:
//   prep(transposes+ln1) -> QKV -> attn_fused(+Wo+res+ln2) -> FFN1 -> lnm -> FFN2
// ws layout: [0,4M) xn  [4,16M) qkv  [16,20M) x1n  [24,40M) h
//            [40,41.5M) Btqkv  [42,42.25M) Wot  [43,45M) W1t  [45,47M) W2t
#define MB (1048576)
extern "C" void kernel_launch(void* const* d_in, const int* in_sizes, int n_in,
                              void* d_out, int out_size, void* d_ws, size_t ws_size,
                              hipStream_t stream) {
  const float* x    = (const float*)d_in[0];
  const float* pos  = (const float*)d_in[1];
  const float* ori  = (const float*)d_in[2];
  const int*   batch = (const int*)d_in[4];
  const float* ln1g = (const float*)d_in[5];
  const float* ln1b = (const float*)d_in[6];
  const float* ln2g = (const float*)d_in[7];
  const float* ln2b = (const float*)d_in[8];
  const float* Wq = (const float*)d_in[9];
  const float* Wk = (const float*)d_in[10];
  const float* Wv = (const float*)d_in[11];
  const float* Wo = (const float*)d_in[12];
  const float* lnmg = (const float*)d_in[13];
  const float* lnmb = (const float*)d_in[14];
  const float* W1 = (const float*)d_in[15];
  const float* W2 = (const float*)d_in[16];
  float* out = (float*)d_out;

  char* ws = (char*)d_ws;
  u16* xn    = (u16*)(ws + 0);
  u16* qkv   = (u16*)(ws + 4 * MB);
  u16* x1n   = (u16*)(ws + 16 * MB);
  u16* h     = (u16*)(ws + 24 * MB);
  u16* Btqkv = (u16*)(ws + 40 * MB);
  u16* Wot   = (u16*)(ws + 42 * MB);
  u16* W1t   = (u16*)(ws + 43 * MB);
  u16* W2t   = (u16*)(ws + 45 * MB);

  // prep: all transposes + ln1
  prep_kernel<<<dim3(6976), 256, 0, stream>>>(Wq, Wk, Wv, Wo, W1, W2,
                                              Btqkv, Wot, W1t, W2t,
                                              x, ln1g, ln1b, xn);
  // qkv = xn @ [Wq|Wk|Wv]
  gemm128<<<dim3(12, 32, 1), 512, 0, stream>>>(xn, 512, Btqkv, qkv, QKV_LD, 0,
                                               nullptr, 512, 512, 0, 0);
  // attention + Wo + residual + ln2  -> out (x1, f32) and x1n (bf16)
  attn_fused<<<dim3(256), 256, 0, stream>>>(qkv, pos, ori, batch, Wot, x,
                                            ln2g, ln2b, out, x1n);
  // h = x1n @ W1
  gemm128<<<dim3(16, 32, 1), 512, 0, stream>>>(x1n, 512, W1t, h, 2048, 0,
                                               nullptr, 512, 512, 0, 0);
  // h = relu(LN(h))
  ln_kernel<<<dim3(4096), 256, 0, stream>>>(h, lnmg, lnmb, h, 2048, 0, 1);
  // out += h @ W2  (split-K x4, atomic f32; out already holds x1)
  gemm128<<<dim3(4, 32, 4), 512, 0, stream>>>(h, 2048, W2t, out, 512, 1,
                                              nullptr, 512, 2048, 0, 1);
}